// Round 1
// baseline (305.286 us; speedup 1.0000x reference)
//
#include <hip/hip_runtime.h>

#define B_   16
#define NH   12
#define SEQ  1024
#define CD   768
#define HD_  64
#define MTOT (B_ * SEQ)

typedef __attribute__((ext_vector_type(4))) float  f32x4;
typedef __attribute__((ext_vector_type(8))) __bf16 bf16x8;

__device__ __forceinline__ unsigned short f2bf(float f) {
  unsigned u = __float_as_uint(f);
  u = (u + 0x7FFFu + ((u >> 16) & 1u)) >> 16;  // RNE
  return (unsigned short)u;
}

__device__ __forceinline__ void gload16(const void* g, void* l) {
  __builtin_amdgcn_global_load_lds(
      (const __attribute__((address_space(1))) void*)g,
      (__attribute__((address_space(3))) void*)l, 16, 0, 0);
}

// ---- conversion kernels -------------------------------------------------

__global__ void cvt_x_kernel(const float* __restrict__ in,
                             unsigned short* __restrict__ out, int n4) {
  int i = blockIdx.x * blockDim.x + threadIdx.x;
  if (i >= n4) return;
  float4 f = reinterpret_cast<const float4*>(in)[i];
  uint2 o;
  o.x = (unsigned)f2bf(f.x) | ((unsigned)f2bf(f.y) << 16);
  o.y = (unsigned)f2bf(f.z) | ((unsigned)f2bf(f.w) << 16);
  reinterpret_cast<uint2*>(out)[i] = o;
}

// W [K][N] f32 -> Wt [N][K] bf16
__global__ void transpose_cvt_kernel(const float* __restrict__ W,
                                     unsigned short* __restrict__ Wt,
                                     int K, int N) {
  __shared__ float tile[32][33];
  int j0 = blockIdx.x * 32, k0 = blockIdx.y * 32;
  int tx = threadIdx.x, ty = threadIdx.y;  // block (32,8)
  #pragma unroll
  for (int i = 0; i < 4; i++)
    tile[ty + 8 * i][tx] = W[(size_t)(k0 + ty + 8 * i) * N + j0 + tx];
  __syncthreads();
  #pragma unroll
  for (int i = 0; i < 4; i++)
    Wt[(size_t)(j0 + ty + 8 * i) * K + k0 + tx] = f2bf(tile[tx][ty + 8 * i]);
}

// ---- LDS fragment loads -------------------------------------------------

// 64B rows, swizzle ((row>>1)&3)<<4
__device__ __forceinline__ bf16x8 ldsA64(const unsigned short* buf, int row, int g) {
  int byte = (row << 6) + ((g << 4) ^ (((row >> 1) & 3) << 4));
  return *reinterpret_cast<const bf16x8*>((const char*)buf + byte);
}
// 128B rows, swizzle (row&7)<<4
__device__ __forceinline__ bf16x8 lds128(const unsigned short* buf, int row, int cb) {
  int byte = (row << 7) + (cb ^ ((row & 7) << 4));
  return *reinterpret_cast<const bf16x8*>((const char*)buf + byte);
}

// ---- GEMM: C[M][N] = A[M][K] * Bt[N][K]^T, 128x128 tile, 4 waves --------
// MODE 0: qkv epilogue (bf16 scatter to Q(scaled)/K [B,H,N,64], V [B,H,64,N])
// MODE 1: proj epilogue (f32 + bias to d_out)

template <int MODE>
__global__ __launch_bounds__(256, 2)
void gemm_bt_kernel(const unsigned short* __restrict__ A,
                    const unsigned short* __restrict__ Bt, const int K,
                    unsigned short* __restrict__ dstQ,
                    unsigned short* __restrict__ dstK,
                    unsigned short* __restrict__ dstV,
                    float* __restrict__ outF,
                    const float* __restrict__ bias) {
  __shared__ unsigned short As[128 * 32];
  __shared__ unsigned short Bs[128 * 32];
  const int tid = threadIdx.x;
  const int lane = tid & 63;
  const int wave = tid >> 6;
  const int wm = (wave >> 1) << 6;
  const int wn = (wave & 1) << 6;
  const int m0 = blockIdx.x << 7;
  const int j0 = blockIdx.y << 7;

  const int sr = tid >> 2;             // staging row (0..63)
  const int sc = (tid & 3) << 4;       // byte col in 64B row
  const int scs = sc ^ (((sr >> 1) & 3) << 4);  // pre-swizzled source col

  f32x4 acc[4][4] = {};

  const char* ab  = (const char*)(A  + (size_t)(m0 + sr) * K) + scs;
  const char* ab2 = (const char*)(A  + (size_t)(m0 + sr + 64) * K) + scs;
  const char* bb  = (const char*)(Bt + (size_t)(j0 + sr) * K) + scs;
  const char* bb2 = (const char*)(Bt + (size_t)(j0 + sr + 64) * K) + scs;

  for (int k0 = 0; k0 < K; k0 += 32) {
    __syncthreads();
    gload16(ab  + k0 * 2, (char*)As + tid * 16);
    gload16(ab2 + k0 * 2, (char*)As + 4096 + tid * 16);
    gload16(bb  + k0 * 2, (char*)Bs + tid * 16);
    gload16(bb2 + k0 * 2, (char*)Bs + 4096 + tid * 16);
    __syncthreads();
    bf16x8 af[4], bf[4];
    const int g = lane >> 4;
    #pragma unroll
    for (int fr = 0; fr < 4; fr++) af[fr] = ldsA64(As, wm + fr * 16 + (lane & 15), g);
    #pragma unroll
    for (int fn = 0; fn < 4; fn++) bf[fn] = ldsA64(Bs, wn + fn * 16 + (lane & 15), g);
    #pragma unroll
    for (int fr = 0; fr < 4; fr++)
      #pragma unroll
      for (int fn = 0; fn < 4; fn++)
        acc[fr][fn] = __builtin_amdgcn_mfma_f32_16x16x32_bf16(af[fr], bf[fn],
                                                              acc[fr][fn], 0, 0, 0);
  }

  #pragma unroll
  for (int fr = 0; fr < 4; fr++) {
    #pragma unroll
    for (int fn = 0; fn < 4; fn++) {
      const int jb = j0 + wn + fn * 16;          // uniform per fragment
      const int jl = jb + (lane & 15);
      const int mb = m0 + wm + fr * 16 + ((lane >> 4) << 2);
      if (MODE == 0) {
        const int sec = jb / CD;                 // 0=Q 1=K 2=V
        const int h = (jb - sec * CD) >> 6;
        const int d = jl & 63;
        #pragma unroll
        for (int r = 0; r < 4; r++) {
          const int m = mb + r;
          const int b = m >> 10, n = m & 1023;
          const float v = acc[fr][fn][r];
          if (sec == 0)
            dstQ[((size_t)(b * NH + h) * SEQ + n) * HD_ + d] = f2bf(v * 0.125f);
          else if (sec == 1)
            dstK[((size_t)(b * NH + h) * SEQ + n) * HD_ + d] = f2bf(v);
          else
            dstV[((size_t)(b * NH + h) * HD_ + d) * SEQ + n] = f2bf(v);
        }
      } else {
        const float bv = bias[jl];
        #pragma unroll
        for (int r = 0; r < 4; r++) {
          const int m = mb + r;
          outF[(size_t)m * CD + jl] = acc[fr][fn][r] + bv;
        }
      }
    }
  }
}

// ---- flash attention: block = (b*h, 64 q rows), 4 waves x 16 rows -------

__global__ __launch_bounds__(256, 2)
void attn_kernel(const unsigned short* __restrict__ Qg,   // [BH][1024][64] (prescaled)
                 const unsigned short* __restrict__ Kg,   // [BH][1024][64]
                 const unsigned short* __restrict__ Vg,   // [BH][64][1024]
                 unsigned short* __restrict__ Og) {       // [B][1024][768] bf16
  __shared__ unsigned short Qs[64 * 64];
  __shared__ unsigned short Ks[64 * 64];
  __shared__ unsigned short Vs[64 * 64];
  __shared__ unsigned short Ps[4 * 16 * 80];  // per-wave [16 q][80] (16B-aligned rows)

  const int tid = threadIdx.x;
  const int lane = tid & 63;
  const int wave = tid >> 6;
  const int bh = blockIdx.x;
  const int q0 = blockIdx.y * 64;

  const int sr = tid >> 3;             // staging row (0..31), 128B rows
  const int sc = (tid & 7) << 4;
  const int scs = sc ^ ((sr & 7) << 4);

  {
    const char* qb = (const char*)(Qg + ((size_t)bh * SEQ + q0) * HD_);
    gload16(qb + sr * 128 + scs, (char*)Qs + tid * 16);
    gload16(qb + (sr + 32) * 128 + scs, (char*)Qs + 4096 + tid * 16);
  }
  __syncthreads();
  bf16x8 qf[2];
  {
    const int row = wave * 16 + (lane & 15);
    const int cb = (lane >> 4) << 4;
    qf[0] = lds128(Qs, row, cb);
    qf[1] = lds128(Qs, row, cb + 64);
  }

  f32x4 o[4] = {};
  float mrun[4], lrun[4];
  #pragma unroll
  for (int r = 0; r < 4; r++) { mrun[r] = -1e30f; lrun[r] = 0.f; }

  const char* kb0 = (const char*)(Kg + (size_t)bh * SEQ * HD_);
  const char* vb0 = (const char*)(Vg + (size_t)bh * HD_ * SEQ);

  for (int kv0 = 0; kv0 < SEQ; kv0 += 64) {
    __syncthreads();
    gload16(kb0 + (kv0 + sr) * 128 + scs, (char*)Ks + tid * 16);
    gload16(kb0 + (kv0 + sr + 32) * 128 + scs, (char*)Ks + 4096 + tid * 16);
    gload16(vb0 + sr * 2048 + kv0 * 2 + scs, (char*)Vs + tid * 16);
    gload16(vb0 + (sr + 32) * 2048 + kv0 * 2 + scs, (char*)Vs + 4096 + tid * 16);
    __syncthreads();

    const int cb = (lane >> 4) << 4;
    f32x4 s[4] = {};
    #pragma unroll
    for (int fn = 0; fn < 4; fn++) {
      const int row = fn * 16 + (lane & 15);
      bf16x8 kf0 = lds128(Ks, row, cb);
      bf16x8 kf1 = lds128(Ks, row, cb + 64);
      s[fn] = __builtin_amdgcn_mfma_f32_16x16x32_bf16(qf[0], kf0, s[fn], 0, 0, 0);
      s[fn] = __builtin_amdgcn_mfma_f32_16x16x32_bf16(qf[1], kf1, s[fn], 0, 0, 0);
    }

    // online softmax (rows = q: 4 per lane; cols spread over lane&15 and fn)
    float mnew[4], corr[4], tsum[4];
    #pragma unroll
    for (int r = 0; r < 4; r++) {
      float v = fmaxf(fmaxf(s[0][r], s[1][r]), fmaxf(s[2][r], s[3][r]));
      #pragma unroll
      for (int off = 8; off; off >>= 1) v = fmaxf(v, __shfl_xor(v, off));
      mnew[r] = fmaxf(mrun[r], v);
      corr[r] = __expf(mrun[r] - mnew[r]);
      tsum[r] = 0.f;
    }
    #pragma unroll
    for (int fn = 0; fn < 4; fn++)
      #pragma unroll
      for (int r = 0; r < 4; r++) {
        float p = __expf(s[fn][r] - mnew[r]);
        s[fn][r] = p;
        tsum[r] += p;
      }
    #pragma unroll
    for (int r = 0; r < 4; r++) {
      float v = tsum[r];
      #pragma unroll
      for (int off = 8; off; off >>= 1) v += __shfl_xor(v, off);
      lrun[r] = lrun[r] * corr[r] + v;
      mrun[r] = mnew[r];
    }
    #pragma unroll
    for (int fn = 0; fn < 4; fn++)
      #pragma unroll
      for (int r = 0; r < 4; r++) o[fn][r] *= corr[r];

    // P (D-layout) -> per-wave LDS -> A-fragment layout
    unsigned short* pw = Ps + wave * 1280;
    {
      const int qr = (lane >> 4) << 2;
      const int kvc = lane & 15;
      #pragma unroll
      for (int fn = 0; fn < 4; fn++)
        #pragma unroll
        for (int r = 0; r < 4; r++)
          pw[(qr + r) * 80 + fn * 16 + kvc] = f2bf(s[fn][r]);
    }
    bf16x8 pf0, pf1;
    {
      const int row = lane & 15;
      pf0 = *reinterpret_cast<const bf16x8*>((const char*)pw + row * 160 + cb);
      pf1 = *reinterpret_cast<const bf16x8*>((const char*)pw + row * 160 + cb + 64);
    }
    #pragma unroll
    for (int fn = 0; fn < 4; fn++) {
      const int row = fn * 16 + (lane & 15);
      bf16x8 vf0 = lds128(Vs, row, cb);
      bf16x8 vf1 = lds128(Vs, row, cb + 64);
      o[fn] = __builtin_amdgcn_mfma_f32_16x16x32_bf16(pf0, vf0, o[fn], 0, 0, 0);
      o[fn] = __builtin_amdgcn_mfma_f32_16x16x32_bf16(pf1, vf1, o[fn], 0, 0, 0);
    }
  }

  const int b = bh / NH, h = bh - b * NH;
  #pragma unroll
  for (int fn = 0; fn < 4; fn++) {
    const int d = fn * 16 + (lane & 15);
    #pragma unroll
    for (int r = 0; r < 4; r++) {
      const int q = q0 + wave * 16 + ((lane >> 4) << 2) + r;
      const float val = o[fn][r] / lrun[r];
      Og[((size_t)b * SEQ + q) * CD + h * HD_ + d] = f2bf(val);
    }
  }
}

// ---- launch -------------------------------------------------------------

extern "C" void kernel_launch(void* const* d_in, const int* in_sizes, int n_in,
                              void* d_out, int out_size, void* d_ws, size_t ws_size,
                              hipStream_t stream) {
  const float* x     = (const float*)d_in[0];
  const float* Wqkv  = (const float*)d_in[1];
  const float* Wproj = (const float*)d_in[2];
  const float* bproj = (const float*)d_in[3];

  char* ws = (char*)d_ws;
  // byte offsets (all 1KB-aligned)
  unsigned short* xb  = (unsigned short*)(ws + 0);          //  25165824  x bf16 [16384][768]
  unsigned short* wqT = (unsigned short*)(ws + 25165824);   //   3538944  Wqkv^T bf16 [2304][768]
  unsigned short* wpT = (unsigned short*)(ws + 28704768);   //   1179648  Wproj^T bf16 [768][768]
  unsigned short* Qw  = (unsigned short*)(ws + 29884416);   //  25165824  [B,H,N,64] (prescaled)
  unsigned short* Kw  = (unsigned short*)(ws + 55050240);   //  25165824  [B,H,N,64]
  unsigned short* Vw  = (unsigned short*)(ws + 80216064);   //  25165824  [B,H,64,N]
  unsigned short* ao  = (unsigned short*)(ws + 105381888);  //  25165824  [B,N,768]
  if (ws_size < 130547712ull) return;  // insufficient scratch -> fail visibly

  const int n4 = MTOT * CD / 4;  // 3145728
  cvt_x_kernel<<<n4 / 256, 256, 0, stream>>>(x, xb, n4);
  transpose_cvt_kernel<<<dim3(2304 / 32, 768 / 32), dim3(32, 8), 0, stream>>>(Wqkv, wqT, 768, 2304);
  transpose_cvt_kernel<<<dim3(768 / 32, 768 / 32), dim3(32, 8), 0, stream>>>(Wproj, wpT, 768, 768);

  gemm_bt_kernel<0><<<dim3(128, 18), 256, 0, stream>>>(xb, wqT, 768, Qw, Kw, Vw,
                                                       nullptr, nullptr);
  attn_kernel<<<dim3(B_ * NH, SEQ / 64), 256, 0, stream>>>(Qw, Kw, Vw, ao);
  gemm_bt_kernel<1><<<dim3(128, 6), 256, 0, stream>>>(ao, wpT, 768, nullptr, nullptr,
                                                      nullptr, (float*)d_out, bproj);
}

// Round 2
// 261.196 us; speedup vs baseline: 1.1688x; 1.1688x over previous
//
#include <hip/hip_runtime.h>

#define B_   16
#define NH   12
#define SEQ  1024
#define CD   768
#define HD_  64
#define MTOT (B_ * SEQ)

typedef __attribute__((ext_vector_type(4))) float  f32x4;
typedef __attribute__((ext_vector_type(8))) __bf16 bf16x8;

__device__ __forceinline__ unsigned short f2bf(float f) {
  unsigned u = __float_as_uint(f);
  u = (u + 0x7FFFu + ((u >> 16) & 1u)) >> 16;  // RNE
  return (unsigned short)u;
}

__device__ __forceinline__ void gload16(const void* g, void* l) {
  __builtin_amdgcn_global_load_lds(
      (const __attribute__((address_space(1))) void*)g,
      (__attribute__((address_space(3))) void*)l, 16, 0, 0);
}

// ---- conversion kernels -------------------------------------------------

__global__ void cvt_x_kernel(const float* __restrict__ in,
                             unsigned short* __restrict__ out, int n4) {
  int i = blockIdx.x * blockDim.x + threadIdx.x;
  if (i >= n4) return;
  float4 f = reinterpret_cast<const float4*>(in)[i];
  uint2 o;
  o.x = (unsigned)f2bf(f.x) | ((unsigned)f2bf(f.y) << 16);
  o.y = (unsigned)f2bf(f.z) | ((unsigned)f2bf(f.w) << 16);
  reinterpret_cast<uint2*>(out)[i] = o;
}

// W [K][N] f32 -> Wt [N][K] bf16
__global__ void transpose_cvt_kernel(const float* __restrict__ W,
                                     unsigned short* __restrict__ Wt,
                                     int K, int N) {
  __shared__ float tile[32][33];
  int j0 = blockIdx.x * 32, k0 = blockIdx.y * 32;
  int tx = threadIdx.x, ty = threadIdx.y;  // block (32,8)
  #pragma unroll
  for (int i = 0; i < 4; i++)
    tile[ty + 8 * i][tx] = W[(size_t)(k0 + ty + 8 * i) * N + j0 + tx];
  __syncthreads();
  #pragma unroll
  for (int i = 0; i < 4; i++)
    Wt[(size_t)(j0 + ty + 8 * i) * K + k0 + tx] = f2bf(tile[tx][ty + 8 * i]);
}

// ---- LDS fragment loads -------------------------------------------------

// 64B rows, swizzle ((row>>1)&3)<<4
__device__ __forceinline__ bf16x8 ldsA64(const unsigned short* buf, int row, int g) {
  int byte = (row << 6) + ((g << 4) ^ (((row >> 1) & 3) << 4));
  return *reinterpret_cast<const bf16x8*>((const char*)buf + byte);
}
// 128B rows, swizzle (row&7)<<4
__device__ __forceinline__ bf16x8 lds128(const unsigned short* buf, int row, int cb) {
  int byte = (row << 7) + (cb ^ ((row & 7) << 4));
  return *reinterpret_cast<const bf16x8*>((const char*)buf + byte);
}

// ---- GEMM: C[M][N] = A[M][K] * Bt[N][K]^T, 128x128 tile, 4 waves --------

template <int MODE>
__global__ __launch_bounds__(256, 2)
void gemm_bt_kernel(const unsigned short* __restrict__ A,
                    const unsigned short* __restrict__ Bt, const int K,
                    unsigned short* __restrict__ dstQ,
                    unsigned short* __restrict__ dstK,
                    unsigned short* __restrict__ dstV,
                    float* __restrict__ outF,
                    const float* __restrict__ bias) {
  __shared__ unsigned short As[128 * 32];
  __shared__ unsigned short Bs[128 * 32];
  const int tid = threadIdx.x;
  const int lane = tid & 63;
  const int wave = tid >> 6;
  const int wm = (wave >> 1) << 6;
  const int wn = (wave & 1) << 6;
  const int m0 = blockIdx.x << 7;
  const int j0 = blockIdx.y << 7;

  const int sr = tid >> 2;
  const int sc = (tid & 3) << 4;
  const int scs = sc ^ (((sr >> 1) & 3) << 4);

  f32x4 acc[4][4] = {};

  const char* ab  = (const char*)(A  + (size_t)(m0 + sr) * K) + scs;
  const char* ab2 = (const char*)(A  + (size_t)(m0 + sr + 64) * K) + scs;
  const char* bb  = (const char*)(Bt + (size_t)(j0 + sr) * K) + scs;
  const char* bb2 = (const char*)(Bt + (size_t)(j0 + sr + 64) * K) + scs;

  for (int k0 = 0; k0 < K; k0 += 32) {
    __syncthreads();
    gload16(ab  + k0 * 2, (char*)As + tid * 16);
    gload16(ab2 + k0 * 2, (char*)As + 4096 + tid * 16);
    gload16(bb  + k0 * 2, (char*)Bs + tid * 16);
    gload16(bb2 + k0 * 2, (char*)Bs + 4096 + tid * 16);
    __syncthreads();
    bf16x8 af[4], bf[4];
    const int g = lane >> 4;
    #pragma unroll
    for (int fr = 0; fr < 4; fr++) af[fr] = ldsA64(As, wm + fr * 16 + (lane & 15), g);
    #pragma unroll
    for (int fn = 0; fn < 4; fn++) bf[fn] = ldsA64(Bs, wn + fn * 16 + (lane & 15), g);
    #pragma unroll
    for (int fr = 0; fr < 4; fr++)
      #pragma unroll
      for (int fn = 0; fn < 4; fn++)
        acc[fr][fn] = __builtin_amdgcn_mfma_f32_16x16x32_bf16(af[fr], bf[fn],
                                                              acc[fr][fn], 0, 0, 0);
  }

  #pragma unroll
  for (int fr = 0; fr < 4; fr++) {
    #pragma unroll
    for (int fn = 0; fn < 4; fn++) {
      const int jb = j0 + wn + fn * 16;
      const int jl = jb + (lane & 15);
      const int mb = m0 + wm + fr * 16 + ((lane >> 4) << 2);
      if (MODE == 0) {
        const int sec = jb / CD;                 // 0=Q 1=K 2=V
        const int h = (jb - sec * CD) >> 6;
        const int d = jl & 63;
        #pragma unroll
        for (int r = 0; r < 4; r++) {
          const int m = mb + r;
          const int b = m >> 10, n = m & 1023;
          const float v = acc[fr][fn][r];
          if (sec == 0)
            dstQ[((size_t)(b * NH + h) * SEQ + n) * HD_ + d] = f2bf(v * 0.125f);
          else if (sec == 1)
            dstK[((size_t)(b * NH + h) * SEQ + n) * HD_ + d] = f2bf(v);
          else
            dstV[((size_t)(b * NH + h) * HD_ + d) * SEQ + n] = f2bf(v);
        }
      } else {
        const float bv = bias[jl];
        #pragma unroll
        for (int r = 0; r < 4; r++) {
          const int m = mb + r;
          outF[(size_t)m * CD + jl] = acc[fr][fn][r] + bv;
        }
      }
    }
  }
}

// ---- flash attention: swapped QK^T + in-register softmax + dbuf ---------
// block = (b*h, 64 q rows), 4 waves x 16 q rows each

__global__ __launch_bounds__(256, 4)
void attn_kernel(const unsigned short* __restrict__ Qg,   // [BH][1024][64] (prescaled)
                 const unsigned short* __restrict__ Kg,   // [BH][1024][64]
                 const unsigned short* __restrict__ Vg,   // [BH][64][1024]
                 unsigned short* __restrict__ Og) {       // [B][1024][768] bf16
  __shared__ unsigned short Qs[64 * 64];
  __shared__ unsigned short Ks[2][64 * 64];
  __shared__ unsigned short Vs[2][64 * 64];

  const int tid = threadIdx.x;
  const int lane = tid & 63;
  const int wave = tid >> 6;
  const int bh = blockIdx.x;
  const int q0 = blockIdx.y * 64;

  const int sr = tid >> 3;             // staging row (0..31), 128B rows
  const int scs = ((tid & 7) << 4) ^ ((sr & 7) << 4);

  const char* kb0 = (const char*)(Kg + (size_t)bh * SEQ * HD_);
  const char* vb0 = (const char*)(Vg + (size_t)bh * HD_ * SEQ);

  // prologue: Q + KV tile 0
  {
    const char* qb = (const char*)(Qg + ((size_t)bh * SEQ + q0) * HD_);
    gload16(qb + sr * 128 + scs, (char*)Qs + tid * 16);
    gload16(qb + (sr + 32) * 128 + scs, (char*)Qs + 4096 + tid * 16);
    gload16(kb0 + sr * 128 + scs, (char*)Ks[0] + tid * 16);
    gload16(kb0 + (sr + 32) * 128 + scs, (char*)Ks[0] + 4096 + tid * 16);
    gload16(vb0 + sr * 2048 + scs, (char*)Vs[0] + tid * 16);
    gload16(vb0 + (sr + 32) * 2048 + scs, (char*)Vs[0] + 4096 + tid * 16);
  }
  __syncthreads();

  const int q = lane & 15;
  const int g = lane >> 4;
  const int cb = g << 4;

  bf16x8 qf[2];
  {
    const int row = wave * 16 + q;
    qf[0] = lds128(Qs, row, cb);
    qf[1] = lds128(Qs, row, cb + 64);
  }

  f32x4 o[4] = {};
  float mrun = -1e30f, lrun = 0.f;
  const bool upperHalf = lane >= 32;
  const int srcA = ((g & 1) << 5) + q;   // pulls from lane group 2*(g&1)
  const int srcB = srcA + 16;            // pulls from lane group 2*(g&1)+1

  for (int t = 0; t < 16; t++) {
    const int cur = t & 1;
    if (t < 15) {
      const int kv1 = (t + 1) * 64;
      gload16(kb0 + (kv1 + sr) * 128 + scs, (char*)Ks[cur ^ 1] + tid * 16);
      gload16(kb0 + (kv1 + sr + 32) * 128 + scs, (char*)Ks[cur ^ 1] + 4096 + tid * 16);
      gload16(vb0 + sr * 2048 + kv1 * 2 + scs, (char*)Vs[cur ^ 1] + tid * 16);
      gload16(vb0 + (sr + 32) * 2048 + kv1 * 2 + scs, (char*)Vs[cur ^ 1] + 4096 + tid * 16);
    }

    // swapped QK^T: S^T[kv][q]; lane holds 16 scores for q = lane&15,
    // kv = fn*16 + 4*g + r
    f32x4 s[4] = {};
    #pragma unroll
    for (int fn = 0; fn < 4; fn++) {
      const int row = fn * 16 + q;
      bf16x8 kf0 = lds128(Ks[cur], row, cb);
      bf16x8 kf1 = lds128(Ks[cur], row, cb + 64);
      s[fn] = __builtin_amdgcn_mfma_f32_16x16x32_bf16(kf0, qf[0], s[fn], 0, 0, 0);
      s[fn] = __builtin_amdgcn_mfma_f32_16x16x32_bf16(kf1, qf[1], s[fn], 0, 0, 0);
    }

    // online softmax, fully in-register (row = q, lane-local)
    float vm = fmaxf(fmaxf(fmaxf(s[0][0], s[0][1]), fmaxf(s[0][2], s[0][3])),
                     fmaxf(fmaxf(s[1][0], s[1][1]), fmaxf(s[1][2], s[1][3])));
    vm = fmaxf(vm, fmaxf(fmaxf(fmaxf(s[2][0], s[2][1]), fmaxf(s[2][2], s[2][3])),
                         fmaxf(fmaxf(s[3][0], s[3][1]), fmaxf(s[3][2], s[3][3]))));
    vm = fmaxf(vm, __shfl_xor(vm, 16));
    vm = fmaxf(vm, __shfl_xor(vm, 32));
    const float mnew = fmaxf(mrun, vm);
    const float corr = __expf(mrun - mnew);
    float tsum = 0.f;
    #pragma unroll
    for (int fn = 0; fn < 4; fn++)
      #pragma unroll
      for (int r = 0; r < 4; r++) {
        const float p = __expf(s[fn][r] - mnew);
        s[fn][r] = p;
        tsum += p;
      }
    tsum += __shfl_xor(tsum, 16);
    tsum += __shfl_xor(tsum, 32);
    lrun = lrun * corr + tsum;
    mrun = mnew;

    // pack P rows to bf16 pairs (kv even/odd in lo/hi)
    unsigned pkv[4][2];
    #pragma unroll
    for (int fn = 0; fn < 4; fn++) {
      asm("v_cvt_pk_bf16_f32 %0, %1, %2"
          : "=v"(pkv[fn][0]) : "v"(s[fn][0]), "v"(s[fn][1]));
      asm("v_cvt_pk_bf16_f32 %0, %1, %2"
          : "=v"(pkv[fn][1]) : "v"(s[fn][2]), "v"(s[fn][3]));
    }

    // redistribute S^T -> PV A-fragment: lane needs kv pair c*32+8g+2w from
    // lane 16*(2(g&1)+(w>>1))+q, register pkv[2c+(g>>1)][w&1]
    union { unsigned u[4]; bf16x8 v; } pa0, pa1;
    #pragma unroll
    for (int w = 0; w < 4; w++) {
      const int src = (w & 2) ? srcB : srcA;
      const unsigned a0 = (unsigned)__shfl((int)pkv[0][w & 1], src, 64);
      const unsigned a1 = (unsigned)__shfl((int)pkv[1][w & 1], src, 64);
      const unsigned a2 = (unsigned)__shfl((int)pkv[2][w & 1], src, 64);
      const unsigned a3 = (unsigned)__shfl((int)pkv[3][w & 1], src, 64);
      pa0.u[w] = upperHalf ? a1 : a0;
      pa1.u[w] = upperHalf ? a3 : a2;
    }

    // rescale O (rows q = 4g+r need corr from lane 4g+r)
    float cr[4];
    #pragma unroll
    for (int r = 0; r < 4; r++) cr[r] = __shfl(corr, 4 * g + r, 64);
    #pragma unroll
    for (int fn = 0; fn < 4; fn++)
      #pragma unroll
      for (int r = 0; r < 4; r++) o[fn][r] *= cr[r];

    // PV
    #pragma unroll
    for (int fn = 0; fn < 4; fn++) {
      const int row = fn * 16 + q;
      bf16x8 vf0 = lds128(Vs[cur], row, cb);
      bf16x8 vf1 = lds128(Vs[cur], row, cb + 64);
      o[fn] = __builtin_amdgcn_mfma_f32_16x16x32_bf16(pa0.v, vf0, o[fn], 0, 0, 0);
      o[fn] = __builtin_amdgcn_mfma_f32_16x16x32_bf16(pa1.v, vf1, o[fn], 0, 0, 0);
    }
    __syncthreads();
  }

  const int b = bh / NH, h = bh - b * NH;
  float rl[4];
  #pragma unroll
  for (int r = 0; r < 4; r++) rl[r] = 1.0f / __shfl(lrun, 4 * g + r, 64);
  #pragma unroll
  for (int fn = 0; fn < 4; fn++) {
    const int d = fn * 16 + q;
    #pragma unroll
    for (int r = 0; r < 4; r++) {
      const int qq = q0 + wave * 16 + 4 * g + r;
      Og[((size_t)b * SEQ + qq) * CD + h * HD_ + d] = f2bf(o[fn][r] * rl[r]);
    }
  }
}

// ---- launch -------------------------------------------------------------

extern "C" void kernel_launch(void* const* d_in, const int* in_sizes, int n_in,
                              void* d_out, int out_size, void* d_ws, size_t ws_size,
                              hipStream_t stream) {
  const float* x     = (const float*)d_in[0];
  const float* Wqkv  = (const float*)d_in[1];
  const float* Wproj = (const float*)d_in[2];
  const float* bproj = (const float*)d_in[3];

  char* ws = (char*)d_ws;
  unsigned short* xb  = (unsigned short*)(ws + 0);
  unsigned short* wqT = (unsigned short*)(ws + 25165824);
  unsigned short* wpT = (unsigned short*)(ws + 28704768);
  unsigned short* Qw  = (unsigned short*)(ws + 29884416);
  unsigned short* Kw  = (unsigned short*)(ws + 55050240);
  unsigned short* Vw  = (unsigned short*)(ws + 80216064);
  unsigned short* ao  = (unsigned short*)(ws + 105381888);
  if (ws_size < 130547712ull) return;

  const int n4 = MTOT * CD / 4;
  cvt_x_kernel<<<n4 / 256, 256, 0, stream>>>(x, xb, n4);
  transpose_cvt_kernel<<<dim3(2304 / 32, 768 / 32), dim3(32, 8), 0, stream>>>(Wqkv, wqT, 768, 2304);
  transpose_cvt_kernel<<<dim3(768 / 32, 768 / 32), dim3(32, 8), 0, stream>>>(Wproj, wpT, 768, 768);

  gemm_bt_kernel<0><<<dim3(128, 18), 256, 0, stream>>>(xb, wqT, 768, Qw, Kw, Vw,
                                                       nullptr, nullptr);
  attn_kernel<<<dim3(B_ * NH, SEQ / 64), 256, 0, stream>>>(Qw, Kw, Vw, ao);
  gemm_bt_kernel<1><<<dim3(128, 6), 256, 0, stream>>>(ao, wpT, 768, nullptr, nullptr,
                                                      nullptr, (float*)d_out, bproj);
}

// Round 3
// 222.825 us; speedup vs baseline: 1.3701x; 1.1722x over previous
//
#include <hip/hip_runtime.h>

#define B_   16
#define NH   12
#define SEQ  1024
#define CD   768
#define HD_  64
#define MTOT (B_ * SEQ)
// 1/sqrt(64) * log2(e): QK^T scores land in log2 domain for exp2
#define QSCALE 0.18033688f

typedef __attribute__((ext_vector_type(4)))  float  f32x4;
typedef __attribute__((ext_vector_type(16))) float  f32x16;
typedef __attribute__((ext_vector_type(8)))  __bf16 bf16x8;
typedef __attribute__((ext_vector_type(2)))  unsigned u32x2;

__device__ __forceinline__ unsigned short f2bf(float f) {
  unsigned u = __float_as_uint(f);
  u = (u + 0x7FFFu + ((u >> 16) & 1u)) >> 16;  // RNE
  return (unsigned short)u;
}

__device__ __forceinline__ void gload16(const void* g, void* l) {
  __builtin_amdgcn_global_load_lds(
      (const __attribute__((address_space(1))) void*)g,
      (__attribute__((address_space(3))) void*)l, 16, 0, 0);
}

// v_permlane32_swap_b32: exchanges dst.high(lanes32-63) with src.low(lanes0-31).
// returns {new_dst, new_src}.
__device__ __forceinline__ u32x2 pswap(unsigned x, unsigned y) {
  return __builtin_amdgcn_permlane32_swap(x, y, false, false);
}

// ---- conversion kernels -------------------------------------------------

__global__ void cvt_x_kernel(const float* __restrict__ in,
                             unsigned short* __restrict__ out, int n4) {
  int i = blockIdx.x * blockDim.x + threadIdx.x;
  if (i >= n4) return;
  float4 f = reinterpret_cast<const float4*>(in)[i];
  uint2 o;
  o.x = (unsigned)f2bf(f.x) | ((unsigned)f2bf(f.y) << 16);
  o.y = (unsigned)f2bf(f.z) | ((unsigned)f2bf(f.w) << 16);
  reinterpret_cast<uint2*>(out)[i] = o;
}

// W [K][N] f32 -> Wt [N][K] bf16
__global__ void transpose_cvt_kernel(const float* __restrict__ W,
                                     unsigned short* __restrict__ Wt,
                                     int K, int N) {
  __shared__ float tile[32][33];
  int j0 = blockIdx.x * 32, k0 = blockIdx.y * 32;
  int tx = threadIdx.x, ty = threadIdx.y;  // block (32,8)
  #pragma unroll
  for (int i = 0; i < 4; i++)
    tile[ty + 8 * i][tx] = W[(size_t)(k0 + ty + 8 * i) * N + j0 + tx];
  __syncthreads();
  #pragma unroll
  for (int i = 0; i < 4; i++)
    Wt[(size_t)(j0 + ty + 8 * i) * K + k0 + tx] = f2bf(tile[tx][ty + 8 * i]);
}

// ---- LDS fragment loads -------------------------------------------------

// 64B rows, swizzle ((row>>1)&3)<<4
__device__ __forceinline__ bf16x8 ldsA64(const unsigned short* buf, int row, int g) {
  int byte = (row << 6) + ((g << 4) ^ (((row >> 1) & 3) << 4));
  return *reinterpret_cast<const bf16x8*>((const char*)buf + byte);
}
// 128B rows, swizzle (row&7)<<4
__device__ __forceinline__ bf16x8 lds128(const unsigned short* buf, int row, int cb) {
  int byte = (row << 7) + (cb ^ ((row & 7) << 4));
  return *reinterpret_cast<const bf16x8*>((const char*)buf + byte);
}

// ---- GEMM: C[M][N] = A[M][K] * Bt[N][K]^T, 128x128 tile, 4 waves --------

template <int MODE>
__global__ __launch_bounds__(256, 2)
void gemm_bt_kernel(const unsigned short* __restrict__ A,
                    const unsigned short* __restrict__ Bt, const int K,
                    unsigned short* __restrict__ dstQ,
                    unsigned short* __restrict__ dstK,
                    unsigned short* __restrict__ dstV,
                    float* __restrict__ outF,
                    const float* __restrict__ bias) {
  __shared__ unsigned short As[128 * 32];
  __shared__ unsigned short Bs[128 * 32];
  const int tid = threadIdx.x;
  const int lane = tid & 63;
  const int wave = tid >> 6;
  const int wm = (wave >> 1) << 6;
  const int wn = (wave & 1) << 6;
  const int m0 = blockIdx.x << 7;
  const int j0 = blockIdx.y << 7;

  const int sr = tid >> 2;
  const int sc = (tid & 3) << 4;
  const int scs = sc ^ (((sr >> 1) & 3) << 4);

  f32x4 acc[4][4] = {};

  const char* ab  = (const char*)(A  + (size_t)(m0 + sr) * K) + scs;
  const char* ab2 = (const char*)(A  + (size_t)(m0 + sr + 64) * K) + scs;
  const char* bb  = (const char*)(Bt + (size_t)(j0 + sr) * K) + scs;
  const char* bb2 = (const char*)(Bt + (size_t)(j0 + sr + 64) * K) + scs;

  for (int k0 = 0; k0 < K; k0 += 32) {
    __syncthreads();
    gload16(ab  + k0 * 2, (char*)As + tid * 16);
    gload16(ab2 + k0 * 2, (char*)As + 4096 + tid * 16);
    gload16(bb  + k0 * 2, (char*)Bs + tid * 16);
    gload16(bb2 + k0 * 2, (char*)Bs + 4096 + tid * 16);
    __syncthreads();
    bf16x8 af[4], bf[4];
    const int g = lane >> 4;
    #pragma unroll
    for (int fr = 0; fr < 4; fr++) af[fr] = ldsA64(As, wm + fr * 16 + (lane & 15), g);
    #pragma unroll
    for (int fn = 0; fn < 4; fn++) bf[fn] = ldsA64(Bs, wn + fn * 16 + (lane & 15), g);
    #pragma unroll
    for (int fr = 0; fr < 4; fr++)
      #pragma unroll
      for (int fn = 0; fn < 4; fn++)
        acc[fr][fn] = __builtin_amdgcn_mfma_f32_16x16x32_bf16(af[fr], bf[fn],
                                                              acc[fr][fn], 0, 0, 0);
  }

  #pragma unroll
  for (int fr = 0; fr < 4; fr++) {
    #pragma unroll
    for (int fn = 0; fn < 4; fn++) {
      const int jb = j0 + wn + fn * 16;
      const int jl = jb + (lane & 15);
      const int mb = m0 + wm + fr * 16 + ((lane >> 4) << 2);
      if (MODE == 0) {
        const int sec = jb / CD;                 // 0=Q 1=K 2=V
        const int h = (jb - sec * CD) >> 6;
        const int d = jl & 63;
        #pragma unroll
        for (int r = 0; r < 4; r++) {
          const int m = mb + r;
          const int b = m >> 10, n = m & 1023;
          const float v = acc[fr][fn][r];
          if (sec == 0)
            dstQ[((size_t)(b * NH + h) * SEQ + n) * HD_ + d] = f2bf(v * QSCALE);
          else if (sec == 1)
            dstK[((size_t)(b * NH + h) * SEQ + n) * HD_ + d] = f2bf(v);
          else
            dstV[((size_t)(b * NH + h) * HD_ + d) * SEQ + n] = f2bf(v);
        }
      } else {
        const float bv = bias[jl];
        #pragma unroll
        for (int r = 0; r < 4; r++) {
          const int m = mb + r;
          outF[(size_t)m * CD + jl] = acc[fr][fn][r] + bv;
        }
      }
    }
  }
}

// ---- flash attention: 32x32 swapped QK^T, in-lane softmax, permlane PV --
// block = (b*h, 128 q rows), 4 waves x 32 q rows each, KVBLK=64 dbuf

__global__ __launch_bounds__(256, 4)
void attn_kernel(const unsigned short* __restrict__ Qg,   // [BH][1024][64] (pre-scaled by QSCALE)
                 const unsigned short* __restrict__ Kg,   // [BH][1024][64]
                 const unsigned short* __restrict__ Vg,   // [BH][64][1024]
                 unsigned short* __restrict__ Og) {       // [B][1024][768] bf16
  // [0,8K) K0 | [8K,16K) V0 | [16K,24K) K1 | [24K,32K) V1 ; Q aliases [16K,32K)
  __shared__ unsigned short ldsbuf[16384];
  __shared__ float sStat[2][4][32];  // [0]=corr, [1]=lsum

  unsigned short* const K0 = ldsbuf;
  unsigned short* const V0 = ldsbuf + 4096;
  unsigned short* const K1 = ldsbuf + 8192;
  unsigned short* const V1 = ldsbuf + 12288;
  unsigned short* const Qs = ldsbuf + 8192;  // 16KB, prologue only

  const int tid = threadIdx.x;
  const int lane = tid & 63;
  const int wave = tid >> 6;
  const int half = lane >> 5;
  const int q_l = lane & 31;
  const int bh = blockIdx.x;
  const int q0 = blockIdx.y * 128;

  const int sr = tid >> 3;                       // staging row 0..31
  const int scs = ((tid & 7) << 4) ^ ((sr & 7) << 4);

  const char* kb0 = (const char*)(Kg + (size_t)bh * SEQ * HD_);
  const char* vb0 = (const char*)(Vg + (size_t)bh * HD_ * SEQ);

  // prologue: Q (128 rows) + KV tile 0
  {
    const char* qb = (const char*)(Qg + ((size_t)bh * SEQ + q0) * HD_);
    #pragma unroll
    for (int i = 0; i < 4; i++)
      gload16(qb + (sr + 32 * i) * 128 + scs, (char*)Qs + (tid + 256 * i) * 16);
    gload16(kb0 + sr * 128 + scs, (char*)K0 + tid * 16);
    gload16(kb0 + (sr + 32) * 128 + scs, (char*)K0 + 4096 + tid * 16);
    gload16(vb0 + sr * 2048 + scs, (char*)V0 + tid * 16);
    gload16(vb0 + (sr + 32) * 2048 + scs, (char*)V0 + 4096 + tid * 16);
  }
  __syncthreads();

  bf16x8 qf[4];
  #pragma unroll
  for (int c = 0; c < 4; c++)
    qf[c] = lds128(Qs, wave * 32 + q_l, 32 * c + 16 * half);
  __syncthreads();  // all waves done with Qs before buf1 prefetch overwrites it

  f32x16 o0 = {}, o1 = {};
  float mrun = -1e30f, lrun = 0.f;

  for (int t = 0; t < 16; t++) {
    const unsigned short* const Kc = (t & 1) ? K1 : K0;
    const unsigned short* const Vc = (t & 1) ? V1 : V0;
    unsigned short* const Kn = (t & 1) ? K0 : K1;
    unsigned short* const Vn = (t & 1) ? V0 : V1;
    if (t < 15) {
      const int kv1 = (t + 1) * 64;
      gload16(kb0 + (kv1 + sr) * 128 + scs, (char*)Kn + tid * 16);
      gload16(kb0 + (kv1 + sr + 32) * 128 + scs, (char*)Kn + 4096 + tid * 16);
      gload16(vb0 + sr * 2048 + kv1 * 2 + scs, (char*)Vn + tid * 16);
      gload16(vb0 + (sr + 32) * 2048 + kv1 * 2 + scs, (char*)Vn + 4096 + tid * 16);
    }

    // swapped QK^T: S^T tiles; lane pair (l, l+32) holds q-row l&31's 64 scores
    f32x16 s0 = {}, s1 = {};
    #pragma unroll
    for (int c = 0; c < 4; c++) {
      bf16x8 kf0 = lds128(Kc, q_l, 32 * c + 16 * half);
      bf16x8 kf1 = lds128(Kc, 32 + q_l, 32 * c + 16 * half);
      s0 = __builtin_amdgcn_mfma_f32_32x32x16_bf16(kf0, qf[c], s0, 0, 0, 0);
      s1 = __builtin_amdgcn_mfma_f32_32x32x16_bf16(kf1, qf[c], s1, 0, 0, 0);
    }

    // row max: 31 in-lane + 1 permlane pair-combine
    float vmax = fmaxf(s0[0], s1[0]);
    #pragma unroll
    for (int r = 1; r < 16; r++) vmax = fmaxf(vmax, fmaxf(s0[r], s1[r]));
    {
      u32x2 mx = pswap(__float_as_uint(vmax), __float_as_uint(vmax));
      vmax = fmaxf(__uint_as_float(mx[0]), __uint_as_float(mx[1]));
    }

    // defer-max (T13): rescale only when some row grew past THR=8 (log2 units)
    if (!__all(vmax <= mrun + 8.0f)) {
      const float mnew = fmaxf(mrun, vmax);
      const float corr = __builtin_amdgcn_exp2f(mrun - mnew);
      mrun = mnew;
      lrun *= corr;
      if (lane < 32) sStat[0][wave][q_l] = corr;
      f32x4 c4[4];
      #pragma unroll
      for (int j = 0; j < 4; j++)
        c4[j] = *reinterpret_cast<const f32x4*>(&sStat[0][wave][4 * half + 8 * j]);
      #pragma unroll
      for (int r = 0; r < 16; r++) {
        const float cc = c4[r >> 2][r & 3];
        o0[r] *= cc;
        o1[r] *= cc;
      }
    }

    // P = exp2(S - m), row-sum
    float tsum = 0.f;
    #pragma unroll
    for (int r = 0; r < 16; r++) {
      const float p0 = __builtin_amdgcn_exp2f(s0[r] - mrun);
      const float p1 = __builtin_amdgcn_exp2f(s1[r] - mrun);
      s0[r] = p0; s1[r] = p1;
      tsum += p0 + p1;
    }
    {
      u32x2 ts = pswap(__float_as_uint(tsum), __float_as_uint(tsum));
      tsum = __uint_as_float(ts[0]) + __uint_as_float(ts[1]);
    }
    lrun += tsum;

    // pack P to bf16 pair-words
    unsigned pk[2][8];
    #pragma unroll
    for (int w = 0; w < 8; w++) {
      asm("v_cvt_pk_bf16_f32 %0, %1, %2"
          : "=v"(pk[0][w]) : "v"(s0[2 * w]), "v"(s0[2 * w + 1]));
      asm("v_cvt_pk_bf16_f32 %0, %1, %2"
          : "=v"(pk[1][w]) : "v"(s1[2 * w]), "v"(s1[2 * w + 1]));
    }

    // PV: per kv-chunk c, 2 permlane swaps build the A-fragment (T12)
    #pragma unroll
    for (int c = 0; c < 4; c++) {
      const int st = c >> 1, cc = c & 1;
      u32x2 rA = pswap(pk[st][4 * cc + 0], pk[st][4 * cc + 2]);
      u32x2 rB = pswap(pk[st][4 * cc + 1], pk[st][4 * cc + 3]);
      union { unsigned u[4]; bf16x8 v; } pa;
      pa.u[0] = rA[0]; pa.u[1] = rB[0]; pa.u[2] = rA[1]; pa.u[3] = rB[1];
      bf16x8 vf0 = lds128(Vc, q_l, 32 * c + 16 * half);
      bf16x8 vf1 = lds128(Vc, 32 + q_l, 32 * c + 16 * half);
      o0 = __builtin_amdgcn_mfma_f32_32x32x16_bf16(pa.v, vf0, o0, 0, 0, 0);
      o1 = __builtin_amdgcn_mfma_f32_32x32x16_bf16(pa.v, vf1, o1, 0, 0, 0);
    }
    __syncthreads();
  }

  // epilogue: 1/l per O-reg q via per-wave stat buffer (broadcast reads)
  if (lane < 32) sStat[1][wave][q_l] = lrun;
  f32x4 rl4[4];
  #pragma unroll
  for (int j = 0; j < 4; j++) {
    f32x4 lv = *reinterpret_cast<const f32x4*>(&sStat[1][wave][4 * half + 8 * j]);
    #pragma unroll
    for (int e = 0; e < 4; e++) rl4[j][e] = __builtin_amdgcn_rcpf(lv[e]);
  }
  const int b = bh / NH, head = bh - b * NH;
  #pragma unroll
  for (int r = 0; r < 16; r++) {
    const int qq = q0 + wave * 32 + (r & 3) + 8 * (r >> 2) + 4 * half;
    const float rl = rl4[r >> 2][r & 3];
    const size_t base = ((size_t)b * SEQ + qq) * CD + head * HD_;
    Og[base + q_l]      = f2bf(o0[r] * rl);
    Og[base + 32 + q_l] = f2bf(o1[r] * rl);
  }
}

// ---- launch -------------------------------------------------------------

extern "C" void kernel_launch(void* const* d_in, const int* in_sizes, int n_in,
                              void* d_out, int out_size, void* d_ws, size_t ws_size,
                              hipStream_t stream) {
  const float* x     = (const float*)d_in[0];
  const float* Wqkv  = (const float*)d_in[1];
  const float* Wproj = (const float*)d_in[2];
  const float* bproj = (const float*)d_in[3];

  char* ws = (char*)d_ws;
  unsigned short* xb  = (unsigned short*)(ws + 0);
  unsigned short* wqT = (unsigned short*)(ws + 25165824);
  unsigned short* wpT = (unsigned short*)(ws + 28704768);
  unsigned short* Qw  = (unsigned short*)(ws + 29884416);
  unsigned short* Kw  = (unsigned short*)(ws + 55050240);
  unsigned short* Vw  = (unsigned short*)(ws + 80216064);
  unsigned short* ao  = (unsigned short*)(ws + 105381888);
  if (ws_size < 130547712ull) return;

  const int n4 = MTOT * CD / 4;
  cvt_x_kernel<<<n4 / 256, 256, 0, stream>>>(x, xb, n4);
  transpose_cvt_kernel<<<dim3(2304 / 32, 768 / 32), dim3(32, 8), 0, stream>>>(Wqkv, wqT, 768, 2304);
  transpose_cvt_kernel<<<dim3(768 / 32, 768 / 32), dim3(32, 8), 0, stream>>>(Wproj, wpT, 768, 768);

  gemm_bt_kernel<0><<<dim3(128, 18), 256, 0, stream>>>(xb, wqT, 768, Qw, Kw, Vw,
                                                       nullptr, nullptr);
  attn_kernel<<<dim3(B_ * NH, SEQ / 128), 256, 0, stream>>>(Qw, Kw, Vw, ao);
  gemm_bt_kernel<1><<<dim3(128, 6), 256, 0, stream>>>(ao, wpT, 768, nullptr, nullptr,
                                                      nullptr, (float*)d_out, bproj);
}